// Round 8
// baseline (239.503 us; speedup 1.0000x reference)
//
#include <hip/hip_runtime.h>

#define NB    4096
#define TSTEP 256
#define BT    2
#define DTC   0.01f

typedef _Float16 h2 __attribute__((ext_vector_type(2)));
typedef _Float16 h8 __attribute__((ext_vector_type(8)));

// tanh(a) = (E-1)/(E+1), E = exp(2a) via v_exp_f32 + v_rcp_f32.
// Upper clamp required: |a| reaches ~5e3 here -> exp2 would overflow -> NaN.
__device__ __forceinline__ float fast_tanh(float a) {
    float t = fminf(a * 2.885390082f, 126.0f);   // 2*log2(e)*a
    float E = __builtin_amdgcn_exp2f(t);
    return (E - 1.0f) * __builtin_amdgcn_rcpf(E + 1.0f);
}
// exp(a) for small |a| (dt-scaled)
__device__ __forceinline__ float fast_exp(float a) {
    return __builtin_amdgcn_exp2f(a * 1.44269504f);
}
// pair-swap (lane ^ 1) via DPP quad_perm [1,0,3,2] -- 1 VALU op, no LDS latency
__device__ __forceinline__ float pair_swap(float v) {
    return __int_as_float(__builtin_amdgcn_mov_dpp(__float_as_int(v), 0xB1, 0xF, 0xF, true));
}

__global__ void __launch_bounds__(64) __attribute__((amdgpu_waves_per_eu(2, 2)))
koopman_kernel(const float* __restrict__ x,
               const float* __restrict__ Wc1, const float* __restrict__ bc1,
               const float* __restrict__ Wc2, const float* __restrict__ bc2,
               const float* __restrict__ Wr1, const float* __restrict__ br1,
               const float* __restrict__ Wr2, const float* __restrict__ br2,
               float* __restrict__ out)
{
    const int lane = threadIdx.x;            // 0..63 = output feature
    const int blk  = blockIdx.x;             // 0..NB/BT-1

    // broadcast copies of y and u as f16 (recurrent state stays fp32)
    __shared__ __align__(16) _Float16 lds_y[BT][64];
    __shared__ __align__(16) _Float16 lds_u[BT][64];

    const bool is_c = (lane < 48);

    // ---- persistent weights, f16-packed: 56 VGPRs, shared by both elements ----
    h2 w1p[32], w2p[24];
    float b1, b2;
    {
        const float* p1 = is_c ? (Wc1 + lane * 64) : (Wr1 + (lane - 48) * 64);
        #pragma unroll
        for (int k = 0; k < 32; ++k) {
            h2 v; v.x = (_Float16)p1[2*k]; v.y = (_Float16)p1[2*k + 1];
            w1p[k] = v;
        }
        const float* p2 = is_c ? (Wc2 + lane * 48) : (Wr2 + (lane - 48) * 16);
        #pragma unroll
        for (int k = 0; k < 24; ++k) {
            const bool valid = is_c || (k >= 16);          // r-lanes: last 8 pairs real
            const int  kk    = is_c ? 2*k : (k >= 16 ? 2*k - 32 : 0);
            h2 v;
            v.x = valid ? (_Float16)p2[kk]     : (_Float16)0.0f;
            v.y = valid ? (_Float16)p2[kk + 1] : (_Float16)0.0f;
            w2p[k] = v;
        }
        b1 = is_c ? bc1[lane] : br1[lane - 48];
        b2 = is_c ? bc2[lane] : br2[lane - 48];
    }
    // layer-2 input window (f16 elems): c-lanes read u[0..47], r-lanes u[16..63]
    // with w2p[0..15]=0 so only u[48..63] (their own tanh block) contributes.
    const int   ubF = is_c ? 0 : 16;
    const float sgn = (lane & 1) ? 1.0f : -1.0f;
    const bool  odd = (lane & 1) != 0;

    // ---- init state ----
    float  ysel[BT];
    float* pout[BT];
    #pragma unroll
    for (int e = 0; e < BT; ++e) {
        const int el = blk * BT + e;
        ysel[e] = x[el * 64 + lane];
        lds_y[e][lane] = (_Float16)ysel[e];
        pout[e] = out + (size_t)el * (TSTEP * 64) + lane;
    }

    // Single-wave workgroup, wave-synchronous LDS (in-order DS pipe): no barriers.
    for (int t = 0; t < TSTEP; ++t) {
        // ---- layer 1: u = tanh(W1 @ y + b1); dot2, 4 chains x 2 elements ----
        float a[BT][4];
        #pragma unroll
        for (int e = 0; e < BT; ++e) { a[e][0] = b1; a[e][1] = 0.0f; a[e][2] = 0.0f; a[e][3] = 0.0f; }
        #pragma unroll
        for (int k = 0; k < 8; ++k) {
            #pragma unroll
            for (int e = 0; e < BT; ++e) {
                const h8 q = *reinterpret_cast<const h8*>(&lds_y[e][k * 8]);
                a[e][0] = __builtin_amdgcn_fdot2(w1p[4*k + 0], __builtin_shufflevector(q, q, 0, 1), a[e][0], false);
                a[e][1] = __builtin_amdgcn_fdot2(w1p[4*k + 1], __builtin_shufflevector(q, q, 2, 3), a[e][1], false);
                a[e][2] = __builtin_amdgcn_fdot2(w1p[4*k + 2], __builtin_shufflevector(q, q, 4, 5), a[e][2], false);
                a[e][3] = __builtin_amdgcn_fdot2(w1p[4*k + 3], __builtin_shufflevector(q, q, 6, 7), a[e][3], false);
            }
        }
        #pragma unroll
        for (int e = 0; e < BT; ++e) {
            const float u = fast_tanh((a[e][0] + a[e][1]) + (a[e][2] + a[e][3]));
            lds_u[e][lane] = (_Float16)u;
        }

        // ---- layer 2: co/re = W2 @ u + b2 ----
        float c[BT][4];
        #pragma unroll
        for (int e = 0; e < BT; ++e) { c[e][0] = b2; c[e][1] = 0.0f; c[e][2] = 0.0f; c[e][3] = 0.0f; }
        #pragma unroll
        for (int k = 0; k < 6; ++k) {
            #pragma unroll
            for (int e = 0; e < BT; ++e) {
                const h8 q = *reinterpret_cast<const h8*>(&lds_u[e][ubF + k * 8]);
                c[e][0] = __builtin_amdgcn_fdot2(w2p[4*k + 0], __builtin_shufflevector(q, q, 0, 1), c[e][0], false);
                c[e][1] = __builtin_amdgcn_fdot2(w2p[4*k + 1], __builtin_shufflevector(q, q, 2, 3), c[e][1], false);
                c[e][2] = __builtin_amdgcn_fdot2(w2p[4*k + 2], __builtin_shufflevector(q, q, 4, 5), c[e][2], false);
                c[e][3] = __builtin_amdgcn_fdot2(w2p[4*k + 3], __builtin_shufflevector(q, q, 6, 7), c[e][3], false);
            }
        }

        // ---- pointwise update (fp32, DPP pair-swaps instead of ds_swizzle) ----
        #pragma unroll
        for (int e = 0; e < BT; ++e) {
            const float co    = (c[e][0] + c[e][1]) + (c[e][2] + c[e][3]);
            const float other = pair_swap(co);
            const float mu = odd ? other : co;     // even slot of pair
            const float om = odd ? co    : other;  // odd slot of pair
            const float scale = fast_exp(DTC * mu);
            const float omr = om * 1.59154943e-3f; // dt*om/(2*pi): v_sin takes revolutions
            const float sv = __builtin_amdgcn_sinf(omr) * scale;
            const float cv = __builtin_amdgcn_cosf(omr) * scale;
            const float yo = pair_swap(ysel[e]);
            // even lane: c*y_self - s*y_partner ; odd lane: c*y_self + s*y_partner
            const float ycnew = fmaf(cv, ysel[e], sgn * sv * yo);
            const float yrnew = fast_exp(DTC * co) * ysel[e];
            const float ynew  = is_c ? ycnew : yrnew;
            ysel[e] = ynew;
            lds_y[e][lane] = (_Float16)ynew;       // f16 broadcast copy only
            *pout[e] = ynew;
            pout[e] += 64;
        }
    }
}

extern "C" void kernel_launch(void* const* d_in, const int* in_sizes, int n_in,
                              void* d_out, int out_size, void* d_ws, size_t ws_size,
                              hipStream_t stream) {
    const float* x   = (const float*)d_in[0];
    const float* Wc1 = (const float*)d_in[1];
    const float* bc1 = (const float*)d_in[2];
    const float* Wc2 = (const float*)d_in[3];
    const float* bc2 = (const float*)d_in[4];
    const float* Wr1 = (const float*)d_in[5];
    const float* br1 = (const float*)d_in[6];
    const float* Wr2 = (const float*)d_in[7];
    const float* br2 = (const float*)d_in[8];
    float* out = (float*)d_out;

    koopman_kernel<<<dim3(NB / BT), dim3(64), 0, stream>>>(
        x, Wc1, bc1, Wc2, bc2, Wr1, br1, Wr2, br2, out);
}

// Round 9
// 226.541 us; speedup vs baseline: 1.0572x; 1.0572x over previous
//
#include <hip/hip_runtime.h>

#define NB    4096
#define TSTEP 256
#define DTC   0.01f

typedef _Float16 h2 __attribute__((ext_vector_type(2)));
typedef _Float16 h8 __attribute__((ext_vector_type(8)));

// tanh(a) = (E-1)/(E+1), E = exp(2a) via v_exp_f32 + v_rcp_f32.
// Upper clamp required: |a| reaches ~5e3 here -> exp2 would overflow -> NaN.
__device__ __forceinline__ float fast_tanh(float a) {
    float t = fminf(a * 2.885390082f, 126.0f);   // 2*log2(e)*a
    float E = __builtin_amdgcn_exp2f(t);
    return (E - 1.0f) * __builtin_amdgcn_rcpf(E + 1.0f);
}
// exp(a) for small |a| (dt-scaled)
__device__ __forceinline__ float fast_exp(float a) {
    return __builtin_amdgcn_exp2f(a * 1.44269504f);
}
// pair-swap (lane ^ 1) via DPP quad_perm [1,0,3,2] -- 1 VALU op, no LDS latency
__device__ __forceinline__ float pair_swap(float v) {
    return __int_as_float(__builtin_amdgcn_mov_dpp(__float_as_int(v), 0xB1, 0xF, 0xF, true));
}

__global__ void __launch_bounds__(64) __attribute__((amdgpu_waves_per_eu(3, 4)))
koopman_kernel(const float* __restrict__ x,
               const float* __restrict__ Wc1, const float* __restrict__ bc1,
               const float* __restrict__ Wc2, const float* __restrict__ bc2,
               const float* __restrict__ Wr1, const float* __restrict__ br1,
               const float* __restrict__ Wr2, const float* __restrict__ br2,
               float* __restrict__ out)
{
    const int lane = threadIdx.x;            // 0..63 = output feature
    const int blk  = blockIdx.x;             // 0..NB-1, one element per wave

    // broadcast copies of y and u as f16 (recurrent state stays fp32)
    __shared__ __align__(16) _Float16 lds_y[64];
    __shared__ __align__(16) _Float16 lds_u[64];

    const bool is_c = (lane < 48);

    // ---- persistent weights, f16-packed: 56 VGPRs ----
    h2 w1p[32], w2p[24];
    float b1, b2;
    {
        const float* p1 = is_c ? (Wc1 + lane * 64) : (Wr1 + (lane - 48) * 64);
        #pragma unroll
        for (int k = 0; k < 32; ++k) {
            h2 v; v.x = (_Float16)p1[2*k]; v.y = (_Float16)p1[2*k + 1];
            w1p[k] = v;
        }
        const float* p2 = is_c ? (Wc2 + lane * 48) : (Wr2 + (lane - 48) * 16);
        #pragma unroll
        for (int k = 0; k < 24; ++k) {
            const bool valid = is_c || (k >= 16);          // r-lanes: last 8 pairs real
            const int  kk    = is_c ? 2*k : (k >= 16 ? 2*k - 32 : 0);
            h2 v;
            v.x = valid ? (_Float16)p2[kk]     : (_Float16)0.0f;
            v.y = valid ? (_Float16)p2[kk + 1] : (_Float16)0.0f;
            w2p[k] = v;
        }
        b1 = is_c ? bc1[lane] : br1[lane - 48];
        b2 = is_c ? bc2[lane] : br2[lane - 48];
    }
    // layer-2 input window (f16 elems): c-lanes read u[0..47], r-lanes u[16..63]
    // with w2p[0..15]=0 so only u[48..63] (their own tanh block) contributes.
    const int   ubF = is_c ? 0 : 16;
    const float sgn = (lane & 1) ? 1.0f : -1.0f;
    const bool  odd = (lane & 1) != 0;

    // ---- init state ----
    float ysel = x[blk * 64 + lane];
    lds_y[lane] = (_Float16)ysel;
    float* pout = out + (size_t)blk * (TSTEP * 64) + lane;

    // Single-wave workgroup, wave-synchronous LDS (in-order DS pipe): no barriers.
    for (int t = 0; t < TSTEP; ++t) {
        // ---- layer 1: u = tanh(W1 @ y + b1); v_dot2_f32_f16, 4 chains ----
        float a0 = b1, a1 = 0.0f, a2 = 0.0f, a3 = 0.0f;
        #pragma unroll
        for (int k = 0; k < 8; ++k) {
            const h8 q = *reinterpret_cast<const h8*>(&lds_y[k * 8]);   // uniform b128
            a0 = __builtin_amdgcn_fdot2(w1p[4*k + 0], __builtin_shufflevector(q, q, 0, 1), a0, false);
            a1 = __builtin_amdgcn_fdot2(w1p[4*k + 1], __builtin_shufflevector(q, q, 2, 3), a1, false);
            a2 = __builtin_amdgcn_fdot2(w1p[4*k + 2], __builtin_shufflevector(q, q, 4, 5), a2, false);
            a3 = __builtin_amdgcn_fdot2(w1p[4*k + 3], __builtin_shufflevector(q, q, 6, 7), a3, false);
        }
        const float u = fast_tanh((a0 + a1) + (a2 + a3));
        lds_u[lane] = (_Float16)u;

        // ---- layer 2: co/re = W2 @ u + b2 ----
        float c0 = b2, c1 = 0.0f, c2 = 0.0f, c3 = 0.0f;
        #pragma unroll
        for (int k = 0; k < 6; ++k) {
            const h8 q = *reinterpret_cast<const h8*>(&lds_u[ubF + k * 8]);
            c0 = __builtin_amdgcn_fdot2(w2p[4*k + 0], __builtin_shufflevector(q, q, 0, 1), c0, false);
            c1 = __builtin_amdgcn_fdot2(w2p[4*k + 1], __builtin_shufflevector(q, q, 2, 3), c1, false);
            c2 = __builtin_amdgcn_fdot2(w2p[4*k + 2], __builtin_shufflevector(q, q, 4, 5), c2, false);
            c3 = __builtin_amdgcn_fdot2(w2p[4*k + 3], __builtin_shufflevector(q, q, 6, 7), c3, false);
        }
        const float co = (c0 + c1) + (c2 + c3);

        // ---- pointwise update (fp32); one shared exp for scale / r-decay ----
        const float other = pair_swap(co);
        const float mu = odd ? other : co;     // even slot of pair
        const float om = odd ? co    : other;  // odd slot of pair
        const float ex = fast_exp(DTC * (is_c ? mu : co));
        const float omr = om * 1.59154943e-3f; // dt*om/(2*pi): v_sin takes revolutions
        const float sv = __builtin_amdgcn_sinf(omr) * ex;
        const float cv = __builtin_amdgcn_cosf(omr) * ex;
        const float yo = pair_swap(ysel);
        // even lane: c*y_self - s*y_partner ; odd lane: c*y_self + s*y_partner
        const float ycnew = fmaf(cv, ysel, sgn * sv * yo);
        const float yrnew = ex * ysel;
        const float ynew  = is_c ? ycnew : yrnew;
        ysel = ynew;
        lds_y[lane] = (_Float16)ynew;          // f16 broadcast copy only
        *pout = ynew;
        pout += 64;
    }
}

extern "C" void kernel_launch(void* const* d_in, const int* in_sizes, int n_in,
                              void* d_out, int out_size, void* d_ws, size_t ws_size,
                              hipStream_t stream) {
    const float* x   = (const float*)d_in[0];
    const float* Wc1 = (const float*)d_in[1];
    const float* bc1 = (const float*)d_in[2];
    const float* Wc2 = (const float*)d_in[3];
    const float* bc2 = (const float*)d_in[4];
    const float* Wr1 = (const float*)d_in[5];
    const float* br1 = (const float*)d_in[6];
    const float* Wr2 = (const float*)d_in[7];
    const float* br2 = (const float*)d_in[8];
    float* out = (float*)d_out;

    koopman_kernel<<<dim3(NB), dim3(64), 0, stream>>>(
        x, Wc1, bc1, Wc2, bc2, Wr1, br1, Wr2, br2, out);
}

// Round 10
// 123.178 us; speedup vs baseline: 1.9444x; 1.8391x over previous
//
#include <hip/hip_runtime.h>

#define NB    4096
#define TSTEP 256
#define EPB   16      // batch elements per block (= MFMA N)
#define DTC   0.01f

typedef _Float16 h8 __attribute__((ext_vector_type(8)));
typedef _Float16 h4 __attribute__((ext_vector_type(4)));
typedef float    f4 __attribute__((ext_vector_type(4)));

#define KE  0.014426950409f   // dt * log2(e)
#define REV 1.59154943e-3f    // dt / (2*pi)  (v_sin/v_cos take revolutions)

// tanh(a) = (E-1)/(E+1), E=exp(2a); upper clamp only (exp2(-inf)->0 -> -1 cleanly)
__device__ __forceinline__ float fast_tanh(float a) {
    float t = fminf(a * 2.885390082f, 126.0f);
    float E = __builtin_amdgcn_exp2f(t);
    return (E - 1.0f) * __builtin_amdgcn_rcpf(E + 1.0f);
}

// LDS map (bytes): y16 f16[16][72] @0 (2304) | u16 f16[16][72] @2304 | y32 f32[16][68] @4608 (4352)
#define U16B  2304
#define Y32B  4608

__global__ void __launch_bounds__(256)
koopman_kernel(const float* __restrict__ x,
               const float* __restrict__ Wc1, const float* __restrict__ bc1,
               const float* __restrict__ Wc2, const float* __restrict__ bc2,
               const float* __restrict__ Wr1, const float* __restrict__ br1,
               const float* __restrict__ Wr2, const float* __restrict__ br2,
               float* __restrict__ out)
{
    const int tid  = threadIdx.x;
    const int lane = tid & 63;
    const int w    = tid >> 6;          // wave id: owns feature tile [16w, 16w+16)
    const int blk  = blockIdx.x;

    __shared__ __align__(16) unsigned char L[Y32B + 16*272];

    const int e = lane & 15;            // elem column (B/D col, A row-within-tile)
    const int g = lane >> 4;            // k-group

    // ---- persistent A fragments (f16 weights): 16 VGPRs total ----
    const int fa = 16*w + e;            // this lane's A row (feature)
    h8 a1lo, a1hi, a2lo, a2hi;
    {
        const float* r1 = (fa < 48) ? (Wc1 + fa*64) : (Wr1 + (fa-48)*64);
        #pragma unroll
        for (int i = 0; i < 8; ++i) {
            a1lo[i] = (_Float16)r1[8*g + i];
            a1hi[i] = (_Float16)r1[32 + 8*g + i];
        }
        #pragma unroll
        for (int i = 0; i < 8; ++i) {   // stacked block-diag layer 2 (64x64, zero-padded)
            const int k0 = 8*g + i, k1 = k0 + 32;
            float v0, v1;
            if (fa < 48) {
                v0 = (k0 < 48) ? Wc2[fa*48 + k0] : 0.0f;
                v1 = (k1 < 48) ? Wc2[fa*48 + k1] : 0.0f;
            } else {
                v0 = (k0 >= 48) ? Wr2[(fa-48)*16 + (k0-48)] : 0.0f;
                v1 = (k1 >= 48) ? Wr2[(fa-48)*16 + (k1-48)] : 0.0f;
            }
            a2lo[i] = (_Float16)v0;
            a2hi[i] = (_Float16)v1;
        }
    }
    // biases + y state in C/D layout: feat = 16w + 4g + r, elem = e
    float b1v[4], b2v[4], ys[4];
    #pragma unroll
    for (int r = 0; r < 4; ++r) {
        const int f = 16*w + 4*g + r;
        b1v[r] = (f < 48) ? bc1[f] : br1[f-48];
        b2v[r] = (f < 48) ? bc2[f] : br2[f-48];
        ys[r]  = x[(blk*EPB + e)*64 + f];
    }
    const bool cwave = (w < 3);         // waves 0-2: complex pairs; wave 3: real modes

    // ---- loop-invariant addresses ----
    const int rdoff  = e*144 + 16*g;                   // B-frag b128 read
    const int wroff  = e*144 + (16*w + 4*g)*2;         // f16 b64 write
    const int w32off = Y32B + e*272 + (16*w + 4*g)*4;  // f32 b128 write
    const int sel = tid >> 4, sf4 = (tid & 15)*4;      // store-phase mapping
    const int stoff = Y32B + sel*272 + sf4*4;
    float* gp = out + (size_t)(blk*EPB + sel) * (TSTEP*64) + sf4;

    // ---- initial y16 fill (coalesced, f16 broadcast copy) ----
    {
        const f4 xv = *reinterpret_cast<const f4*>(x + (blk*EPB + sel)*64 + sf4);
        h4 p; p[0]=(_Float16)xv[0]; p[1]=(_Float16)xv[1]; p[2]=(_Float16)xv[2]; p[3]=(_Float16)xv[3];
        *reinterpret_cast<h4*>(L + sel*144 + sf4*2) = p;
    }
    __syncthreads();

    for (int t = 0; t < TSTEP; ++t) {
        // ---- layer 1: u = tanh(W1s @ y + b1) on the matrix pipe ----
        const h8 by0 = *reinterpret_cast<const h8*>(L + rdoff);
        const h8 by1 = *reinterpret_cast<const h8*>(L + rdoff + 64);
        f4 a = {b1v[0], b1v[1], b1v[2], b1v[3]};
        a = __builtin_amdgcn_mfma_f32_16x16x32_f16(a1lo, by0, a, 0, 0, 0);
        a = __builtin_amdgcn_mfma_f32_16x16x32_f16(a1hi, by1, a, 0, 0, 0);
        h4 up;
        up[0]=(_Float16)fast_tanh(a[0]); up[1]=(_Float16)fast_tanh(a[1]);
        up[2]=(_Float16)fast_tanh(a[2]); up[3]=(_Float16)fast_tanh(a[3]);
        *reinterpret_cast<h4*>(L + U16B + wroff) = up;
        __syncthreads();

        // ---- layer 2: co/re = W2s @ u + b2 ----
        const h8 bu0 = *reinterpret_cast<const h8*>(L + U16B + rdoff);
        const h8 bu1 = *reinterpret_cast<const h8*>(L + U16B + rdoff + 64);
        f4 c = {b2v[0], b2v[1], b2v[2], b2v[3]};
        c = __builtin_amdgcn_mfma_f32_16x16x32_f16(a2lo, bu0, c, 0, 0, 0);
        c = __builtin_amdgcn_mfma_f32_16x16x32_f16(a2hi, bu1, c, 0, 0, 0);

        // ---- pointwise: pairs are register-local, role is wave-uniform ----
        if (cwave) {
            const float sc0 = __builtin_amdgcn_exp2f(KE * c[0]);
            const float sc1 = __builtin_amdgcn_exp2f(KE * c[2]);
            const float s0 = __builtin_amdgcn_sinf(REV * c[1]) * sc0;
            const float c0 = __builtin_amdgcn_cosf(REV * c[1]) * sc0;
            const float s1 = __builtin_amdgcn_sinf(REV * c[3]) * sc1;
            const float c1 = __builtin_amdgcn_cosf(REV * c[3]) * sc1;
            const float n0 = c0*ys[0] - s0*ys[1];
            const float n1 = s0*ys[0] + c0*ys[1];
            const float n2 = c1*ys[2] - s1*ys[3];
            const float n3 = s1*ys[2] + c1*ys[3];
            ys[0]=n0; ys[1]=n1; ys[2]=n2; ys[3]=n3;
        } else {
            ys[0] *= __builtin_amdgcn_exp2f(KE * c[0]);
            ys[1] *= __builtin_amdgcn_exp2f(KE * c[1]);
            ys[2] *= __builtin_amdgcn_exp2f(KE * c[2]);
            ys[3] *= __builtin_amdgcn_exp2f(KE * c[3]);
        }

        // ---- publish y: f16 for next step's matmul, f32 for output staging ----
        h4 yp;
        yp[0]=(_Float16)ys[0]; yp[1]=(_Float16)ys[1]; yp[2]=(_Float16)ys[2]; yp[3]=(_Float16)ys[3];
        *reinterpret_cast<h4*>(L + wroff) = yp;
        f4 yv = {ys[0], ys[1], ys[2], ys[3]};
        *reinterpret_cast<f4*>(L + w32off) = yv;
        __syncthreads();

        // ---- coalesced output store (256B contiguous per element) ----
        const f4 sv = *reinterpret_cast<const f4*>(L + stoff);
        *reinterpret_cast<f4*>(gp) = sv;
        gp += 64;
    }
}

extern "C" void kernel_launch(void* const* d_in, const int* in_sizes, int n_in,
                              void* d_out, int out_size, void* d_ws, size_t ws_size,
                              hipStream_t stream) {
    const float* x   = (const float*)d_in[0];
    const float* Wc1 = (const float*)d_in[1];
    const float* bc1 = (const float*)d_in[2];
    const float* Wc2 = (const float*)d_in[3];
    const float* bc2 = (const float*)d_in[4];
    const float* Wr1 = (const float*)d_in[5];
    const float* br1 = (const float*)d_in[6];
    const float* Wr2 = (const float*)d_in[7];
    const float* br2 = (const float*)d_in[8];
    float* out = (float*)d_out;

    koopman_kernel<<<dim3(NB / EPB), dim3(256), 0, stream>>>(
        x, Wc1, bc1, Wc2, bc2, Wr1, br1, Wr2, br2, out);
}